// Round 8
// baseline (572.868 us; speedup 1.0000x reference)
//
#include <hip/hip_runtime.h>
#include <cstdint>

#define EPS 1e-5f

typedef __attribute__((ext_vector_type(8))) short bf16x8;   // 8 bf16 in 4 VGPRs
typedef __attribute__((ext_vector_type(4))) float f32x4;

// ---------- bf16 helpers (RNE) ----------
__device__ __forceinline__ unsigned short f2bf(float x) {
    uint32_t u = __float_as_uint(x);
    u += 0x7fffu + ((u >> 16) & 1u);
    return (unsigned short)(u >> 16);
}
__device__ __forceinline__ uint32_t pack2(float lo, float hi) {
    return (uint32_t)f2bf(lo) | ((uint32_t)f2bf(hi) << 16);
}
__device__ __forceinline__ float bflo(uint32_t p) { return __uint_as_float(p << 16); }
__device__ __forceinline__ float bfhi(uint32_t p) { return __uint_as_float(p & 0xffff0000u); }

// ---------- async global->LDS, 16B per lane ----------
__device__ __forceinline__ void async_ld16(const void* g, const void* l) {
    __builtin_amdgcn_global_load_lds(
        (const __attribute__((address_space(1))) uint32_t*)(uintptr_t)g,
        (__attribute__((address_space(3))) uint32_t*)(uint32_t)(uintptr_t)l,
        16, 0, 0);
}

// ---------- CSR build ----------
__global__ __launch_bounds__(256) void zero_kernel(int* __restrict__ p, int n) {
    int i = blockIdx.x * 256 + threadIdx.x;
    if (i < n) p[i] = 0;
}

__global__ __launch_bounds__(256) void count_kernel(const int* __restrict__ ei,
                                                    int* __restrict__ deg, int E) {
    int e = blockIdx.x * 256 + threadIdx.x;
    if (e < E) atomicAdd(&deg[ei[E + e]], 1);
}

__global__ __launch_bounds__(1024) void scan_kernel(const int* __restrict__ deg,
                                                    int* __restrict__ offsets,
                                                    int* __restrict__ cursor,
                                                    float* __restrict__ deginv, int N) {
    __shared__ int part[1024];
    const int t = threadIdx.x;
    const int CH = (N + 1023) >> 10;
    const int base = t * CH;
    int s = 0;
    for (int j = 0; j < CH; ++j) {
        int idx = base + j;
        if (idx < N) s += deg[idx];
    }
    part[t] = s;
    __syncthreads();
    for (int off = 1; off < 1024; off <<= 1) {
        int add = (t >= off) ? part[t - off] : 0;
        __syncthreads();
        part[t] += add;
        __syncthreads();
    }
    int run = (t == 0) ? 0 : part[t - 1];
    for (int j = 0; j < CH; ++j) {
        int idx = base + j;
        if (idx < N) {
            offsets[idx] = run;
            cursor[idx]  = run;
            int dgi = deg[idx];
            deginv[idx] = 1.0f / (float)(dgi > 0 ? dgi : 1);
            run += dgi;
        }
    }
    if (t == 1023) offsets[N] = run;
}

__global__ __launch_bounds__(256) void fill_kernel(const int* __restrict__ ei,
                                                   int* __restrict__ cursor,
                                                   int* __restrict__ csr, int E) {
    int e = blockIdx.x * 256 + threadIdx.x;
    if (e < E) {
        int dd = ei[E + e];
        int slot = atomicAdd(&cursor[dd], 1);
        csr[slot] = ei[e];
    }
}

// ---------- embedding + BN(layer 0), bf16 into A_cat[:, 0:512] ----------
__global__ __launch_bounds__(256) void embed_bn_kernel(const int* __restrict__ tok,
                                                       const int* __restrict__ pos,
                                                       const float* __restrict__ vemb,
                                                       const float* __restrict__ pemb,
                                                       const float* __restrict__ gamma,
                                                       const float* __restrict__ beta,
                                                       const float* __restrict__ mean,
                                                       const float* __restrict__ var,
                                                       uint32_t* __restrict__ Acat, int N) {
    const int idx = blockIdx.x * 256 + threadIdx.x;   // one per 4 columns
    if (idx >= N * 128) return;
    const int row = idx >> 7;
    const int c = (idx & 127) * 4;
    const int tk = tok[row];
    const int ps = pos[row];
    const float4 a = *(const float4*)&vemb[(size_t)tk * 512 + c];
    const float4 b = *(const float4*)&pemb[(size_t)ps * 512 + c];
    const float4 g = *(const float4*)&gamma[c];
    const float4 be = *(const float4*)&beta[c];
    const float4 mn = *(const float4*)&mean[c];
    const float4 vr = *(const float4*)&var[c];
    const float y0 = (a.x + b.x - mn.x) * (g.x * rsqrtf(vr.x + EPS)) + be.x;
    const float y1 = (a.y + b.y - mn.y) * (g.y * rsqrtf(vr.y + EPS)) + be.y;
    const float y2 = (a.z + b.z - mn.z) * (g.z * rsqrtf(vr.z + EPS)) + be.z;
    const float y3 = (a.w + b.w - mn.w) * (g.w * rsqrtf(vr.w + EPS)) + be.w;
    uint2 o;
    o.x = pack2(y0, y1);
    o.y = pack2(y2, y3);
    *(uint2*)&Acat[(size_t)row * 512 + (c >> 1)] = o;
}

// ---------- W_cat bf16 [512 rows][1024 k] = [W_root | W_rel] (B^T layout) ----------
// per-layer variant (1 MB Wcat)
__global__ __launch_bounds__(256) void castW_kernel(const float* __restrict__ Wroot,
                                                    const float* __restrict__ Wrel,
                                                    uint32_t* __restrict__ Wcat) {
    const int p = blockIdx.x * 256 + threadIdx.x;   // 262144 pairs total
    const int o  = p >> 9;
    const int dp = p & 511;
    float2 v;
    if (dp < 256) v = *(const float2*)&Wroot[(size_t)o * 512 + dp * 2];
    else          v = *(const float2*)&Wrel[(size_t)o * 512 + (dp - 256) * 2];
    Wcat[(size_t)o * 512 + dp] = pack2(v.x, v.y);
}

// all-4-layers variant (4 MB Wcat4, one launch)
__global__ __launch_bounds__(256) void castW4_kernel(const float* __restrict__ Wroot,
                                                     const float* __restrict__ Wrel,
                                                     uint32_t* __restrict__ Wcat4) {
    const int p = blockIdx.x * 256 + threadIdx.x;   // 4*262144 pairs total
    const int l   = p >> 18;
    const int rem = p & 262143;
    const int o   = rem >> 9;
    const int dp  = rem & 511;
    float2 v;
    if (dp < 256) v = *(const float2*)&Wroot[(size_t)l * 262144 + (size_t)o * 512 + dp * 2];
    else          v = *(const float2*)&Wrel[(size_t)l * 262144 + (size_t)o * 512 + (dp - 256) * 2];
    Wcat4[(size_t)l * 262144 + (size_t)o * 512 + dp] = pack2(v.x, v.y);
}

// ---------- mean aggregation, XCD-column-sharded ----------
// 8 column slices of 128 B (32 uints); slice s runs on blocks with bid%8==s, which the
// dispatcher round-robins onto XCD s -> per-XCD gather working set = N*128B = 2.56 MB,
// L2-resident (vs 20.5 MB full-row: 8x LLC->L2 replication, r0's 153 MB FETCH floor).
// 32 lanes per node-slice (1 dword/lane, 128 B coalesced), 8 node-groups per block,
// 8-deep unrolled edge loop for latency depth. csr reads are group-uniform broadcasts.
__global__ __launch_bounds__(256) void aggregate_sliced(uint32_t* __restrict__ Acat,
                                                        const int* __restrict__ offsets,
                                                        const int* __restrict__ csr,
                                                        const float* __restrict__ deginv,
                                                        int N) {
    const int bid   = blockIdx.x;
    const int slice = bid & 7;                    // -> XCD (perf heuristic only)
    const int chunk = bid >> 3;                   // group of 8 nodes
    const int g     = threadIdx.x >> 5;           // node slot 0..7
    const int l     = threadIdx.x & 31;           // lane within slice
    const int node  = chunk * 8 + g;
    if (node >= N) return;
    const int colbase = slice * 32 + l;           // uint index in first 256-uint half
    const int beg = offsets[node];
    const int end = offsets[node + 1];
    float lo = 0.f, hi = 0.f;
    int e = beg;
    for (; e + 8 <= end; e += 8) {
        const int i0 = csr[e];
        const int i1 = csr[e + 1];
        const int i2 = csr[e + 2];
        const int i3 = csr[e + 3];
        const int i4 = csr[e + 4];
        const int i5 = csr[e + 5];
        const int i6 = csr[e + 6];
        const int i7 = csr[e + 7];
        const uint32_t p0 = Acat[(size_t)i0 * 512 + colbase];
        const uint32_t p1 = Acat[(size_t)i1 * 512 + colbase];
        const uint32_t p2 = Acat[(size_t)i2 * 512 + colbase];
        const uint32_t p3 = Acat[(size_t)i3 * 512 + colbase];
        const uint32_t p4 = Acat[(size_t)i4 * 512 + colbase];
        const uint32_t p5 = Acat[(size_t)i5 * 512 + colbase];
        const uint32_t p6 = Acat[(size_t)i6 * 512 + colbase];
        const uint32_t p7 = Acat[(size_t)i7 * 512 + colbase];
        lo += (bflo(p0) + bflo(p1)) + (bflo(p2) + bflo(p3))
            + (bflo(p4) + bflo(p5)) + (bflo(p6) + bflo(p7));
        hi += (bfhi(p0) + bfhi(p1)) + (bfhi(p2) + bfhi(p3))
            + (bfhi(p4) + bfhi(p5)) + (bfhi(p6) + bfhi(p7));
    }
    for (; e + 4 <= end; e += 4) {
        const int i0 = csr[e];
        const int i1 = csr[e + 1];
        const int i2 = csr[e + 2];
        const int i3 = csr[e + 3];
        const uint32_t p0 = Acat[(size_t)i0 * 512 + colbase];
        const uint32_t p1 = Acat[(size_t)i1 * 512 + colbase];
        const uint32_t p2 = Acat[(size_t)i2 * 512 + colbase];
        const uint32_t p3 = Acat[(size_t)i3 * 512 + colbase];
        lo += (bflo(p0) + bflo(p1)) + (bflo(p2) + bflo(p3));
        hi += (bfhi(p0) + bfhi(p1)) + (bfhi(p2) + bfhi(p3));
    }
    for (; e < end; ++e) {
        const uint32_t p0 = Acat[(size_t)csr[e] * 512 + colbase];
        lo += bflo(p0);
        hi += bfhi(p0);
    }
    const float inv = deginv[node];
    Acat[(size_t)node * 512 + 256 + colbase] = pack2(lo * inv, hi * inv);
}

// ---------- fused GEMM: out = relu(A_cat[M,1024] @ W_cat[512,1024]^T + bias) ----------
// Round-0 structure (BK=32, 16 KiB LDS, plain __syncthreads, max TLP) + bank-conflict
// swizzle: 16B-slot' = slot ^ ((row>>1)&3). Writer pre-swizzles the GLOBAL k-slot
// (LDS dest stays linear for global_load_lds, rule #21); reader XORs the same key,
// which is per-lane constant ((row>>1)&3 == (lm>>1)&3 for all wm/mt/wn/nt).
// Per-16-lane ds_read_b128 phase: 8 bank-groups x 2 lanes = 2-way = free (m136).
// last layer: writes f32 to C. otherwise: applies NEXT layer's BN and writes bf16 to Abn.
__global__ __launch_bounds__(256) void gemm_bt_bias_relu(const unsigned short* __restrict__ A,
                                                         const unsigned short* __restrict__ B,
                                                         const float* __restrict__ bias,
                                                         const float* __restrict__ gamma,
                                                         const float* __restrict__ beta,
                                                         const float* __restrict__ mean,
                                                         const float* __restrict__ var,
                                                         int last,
                                                         float* __restrict__ C,
                                                         unsigned short* __restrict__ Abn,
                                                         int M, int mt, int rpx) {
    __shared__ __align__(16) unsigned short As[128 * 32];
    __shared__ __align__(16) unsigned short Bs[128 * 32];

    const int bid = blockIdx.x;
    const int bm  = (bid & 7) * rpx + ((bid >> 3) >> 2);
    const int bn  = (bid >> 3) & 3;
    if (bm >= mt) return;

    const int t    = threadIdx.x;
    const int lane = t & 63;
    const int wave = t >> 6;
    const int wm = (wave >> 1) * 64;
    const int wn = (wave & 1) * 64;

    const int r  = t >> 2;
    const int kc = t & 3;
    const int kg = kc ^ ((r >> 1) & 3);          // pre-swizzled global 16B k-slot
    int ar0 = bm * 128 + r;      if (ar0 >= M) ar0 = M - 1;
    int ar1 = bm * 128 + r + 64; if (ar1 >= M) ar1 = M - 1;   // (r+64)>>1 & 3 == (r>>1)&3
    const int br0 = bn * 128 + r;
    const int br1 = br0 + 64;

    const unsigned short* ga0 = A + (size_t)ar0 * 1024 + kg * 8;
    const unsigned short* ga1 = A + (size_t)ar1 * 1024 + kg * 8;
    const unsigned short* gb0 = B + (size_t)br0 * 1024 + kg * 8;
    const unsigned short* gb1 = B + (size_t)br1 * 1024 + kg * 8;

    unsigned short* la0 = &As[r * 32 + kc * 8];          // linear LDS dest
    unsigned short* la1 = &As[(r + 64) * 32 + kc * 8];
    unsigned short* lb0 = &Bs[r * 32 + kc * 8];
    unsigned short* lb1 = &Bs[(r + 64) * 32 + kc * 8];

    const f32x4 zero = {0.f, 0.f, 0.f, 0.f};
    f32x4 acc[4][4];
#pragma unroll
    for (int i = 0; i < 4; ++i)
#pragma unroll
        for (int j = 0; j < 4; ++j) acc[i][j] = zero;

    const int lm = lane & 15;
    const int q  = lane >> 4;
    const int qs = (q ^ ((lm >> 1) & 3)) * 8;    // swizzled read slot (per-lane const)

    for (int k0 = 0; k0 < 1024; k0 += 32) {
        async_ld16(ga0 + k0, la0);
        async_ld16(ga1 + k0, la1);
        async_ld16(gb0 + k0, lb0);
        async_ld16(gb1 + k0, lb1);
        __syncthreads();

        bf16x8 afr[4], bfr[4];
#pragma unroll
        for (int mt2 = 0; mt2 < 4; ++mt2)
            afr[mt2] = *(const bf16x8*)&As[(wm + mt2 * 16 + lm) * 32 + qs];
#pragma unroll
        for (int nt = 0; nt < 4; ++nt)
            bfr[nt] = *(const bf16x8*)&Bs[(wn + nt * 16 + lm) * 32 + qs];
#pragma unroll
        for (int mt2 = 0; mt2 < 4; ++mt2)
#pragma unroll
            for (int nt = 0; nt < 4; ++nt)
                acc[mt2][nt] = __builtin_amdgcn_mfma_f32_16x16x32_bf16(afr[mt2], bfr[nt],
                                                                       acc[mt2][nt], 0, 0, 0);
        __syncthreads();
    }

    // epilogue: C/D layout col=lane&15, row=(lane>>4)*4+reg (m89-verified)
#pragma unroll
    for (int nt = 0; nt < 4; ++nt) {
        const int col = bn * 128 + wn + nt * 16 + lm;
        const float bv = bias[col];
        float bn_inv = 0.f, bn_mb = 0.f;
        if (!last) {
            bn_inv = gamma[col] * rsqrtf(var[col] + EPS);
            bn_mb  = mean[col];
        }
        const float bn_beta = last ? 0.f : beta[col];
#pragma unroll
        for (int mt2 = 0; mt2 < 4; ++mt2) {
            const int row0 = bm * 128 + wm + mt2 * 16 + q * 4;
#pragma unroll
            for (int i = 0; i < 4; ++i) {
                const int row = row0 + i;
                if (row < M) {
                    float v = acc[mt2][nt][i] + bv;
                    v = v > 0.f ? v : 0.f;
                    if (last) {
                        C[(size_t)row * 512 + col] = v;
                    } else {
                        const float y = (v - bn_mb) * bn_inv + bn_beta;
                        Abn[(size_t)row * 1024 + col] = f2bf(y);
                    }
                }
            }
        }
    }
}

extern "C" void kernel_launch(void* const* d_in, const int* in_sizes, int n_in,
                              void* d_out, int out_size, void* d_ws, size_t ws_size,
                              hipStream_t stream) {
    const int*   tokens = (const int*)d_in[0];
    const int*   posi   = (const int*)d_in[1];
    const int*   ei     = (const int*)d_in[2];
    const float* vemb   = (const float*)d_in[3];
    const float* pemb   = (const float*)d_in[4];
    const float* gamma  = (const float*)d_in[5];
    const float* beta   = (const float*)d_in[6];
    const float* mean   = (const float*)d_in[7];
    const float* var    = (const float*)d_in[8];
    const float* Wrel   = (const float*)d_in[9];
    const float* brel   = (const float*)d_in[10];
    const float* Wroot  = (const float*)d_in[11];

    const int N = in_sizes[0];
    const int E = in_sizes[2] / 2;
    float* out = (float*)d_out;

    char* w = (char*)d_ws;
    int*      deg     = (int*)(w);                  // N ints
    int*      offsets = (int*)(w + 80000);          // N+1 ints
    int*      cursor  = (int*)(w + 160016);         // N ints
    float*    deginv  = (float*)(w + 240032);       // N floats
    int*      csr     = (int*)(w + 320048);         // E ints
    uint32_t* Acat    = (uint32_t*)(w + 1600064);   // [N][512] uints = [N][1024] bf16
    uint32_t* Wcat    = (uint32_t*)(w + 42560064);  // 1 MB (or 4 MB batched)

    // batched castW needs 4 MB at Wcat (end = 46,754,368 bytes)
    const int batched = (ws_size >= 46754368ull) ? 1 : 0;

    // CSR build (ws re-poisoned each call -> deg must be zeroed here)
    zero_kernel<<<(N + 255) / 256, 256, 0, stream>>>(deg, N);
    count_kernel<<<(E + 255) / 256, 256, 0, stream>>>(ei, deg, E);
    scan_kernel<<<1, 1024, 0, stream>>>(deg, offsets, cursor, deginv, N);
    fill_kernel<<<(E + 255) / 256, 256, 0, stream>>>(ei, cursor, csr, E);

    // embed + layer-0 BN directly into Acat (no f32 x round-trip)
    embed_bn_kernel<<<(N * 128 + 255) / 256, 256, 0, stream>>>(
        tokens, posi, vemb, pemb, gamma, beta, mean, var, Acat, N);

    if (batched)
        castW4_kernel<<<4096, 256, 0, stream>>>(Wroot, Wrel, Wcat);

    const int mt  = (N + 127) >> 7;    // 128-row tiles (158)
    const int rpx = (mt + 7) >> 3;     // row-tiles per XCD (20)
    const int gb  = 8 * rpx * 4;       // grid (640; tail blocks exit early)
    const int gagg = 8 * ((N + 7) / 8);  // sliced aggregate grid (20000)

    for (int l = 0; l < 4; ++l) {
        const int last = (l == 3);
        if (!batched)
            castW_kernel<<<1024, 256, 0, stream>>>(Wroot + (size_t)l * 262144,
                                                   Wrel + (size_t)l * 262144, Wcat);
        aggregate_sliced<<<gagg, 256, 0, stream>>>(Acat, offsets, csr, deginv, N);
        const uint32_t* Wl = batched ? (Wcat + (size_t)l * 262144) : Wcat;
        gemm_bt_bias_relu<<<gb, 256, 0, stream>>>(
            (const unsigned short*)Acat, (const unsigned short*)Wl, brel + l * 512,
            gamma + (l + 1) * 512, beta + (l + 1) * 512,
            mean + (l + 1) * 512, var + (l + 1) * 512,
            last, out, (unsigned short*)Acat, N, mt, rpx);
    }
}

// Round 10
// 524.917 us; speedup vs baseline: 1.0914x; 1.0914x over previous
//
#include <hip/hip_runtime.h>
#include <cstdint>

#define EPS 1e-5f

typedef __attribute__((ext_vector_type(8))) short bf16x8;   // 8 bf16 in 4 VGPRs
typedef __attribute__((ext_vector_type(4))) float f32x4;
typedef __attribute__((ext_vector_type(4))) unsigned int u32x4;  // native vec for nt-store

// ---------- bf16 helpers (RNE) ----------
__device__ __forceinline__ unsigned short f2bf(float x) {
    uint32_t u = __float_as_uint(x);
    u += 0x7fffu + ((u >> 16) & 1u);
    return (unsigned short)(u >> 16);
}
__device__ __forceinline__ uint32_t pack2(float lo, float hi) {
    return (uint32_t)f2bf(lo) | ((uint32_t)f2bf(hi) << 16);
}
__device__ __forceinline__ float bflo(uint32_t p) { return __uint_as_float(p << 16); }
__device__ __forceinline__ float bfhi(uint32_t p) { return __uint_as_float(p & 0xffff0000u); }

// ---------- async global->LDS, 16B per lane ----------
__device__ __forceinline__ void async_ld16(const void* g, const void* l) {
    __builtin_amdgcn_global_load_lds(
        (const __attribute__((address_space(1))) uint32_t*)(uintptr_t)g,
        (__attribute__((address_space(3))) uint32_t*)(uint32_t)(uintptr_t)l,
        16, 0, 0);
}

// ---------- CSR build ----------
__global__ __launch_bounds__(256) void count_kernel(const int* __restrict__ ei,
                                                    int* __restrict__ deg, int E) {
    int e = blockIdx.x * 256 + threadIdx.x;
    if (e < E) atomicAdd(&deg[ei[E + e]], 1);
}

// LDS-staged scan: coalesced deg loads, prefix over 1024 chunk-partials,
// run values staged back into LDS, coalesced offsets/cursor writeout.
// deginv is no longer produced (aggregate derives 1/deg from end-beg).
__global__ __launch_bounds__(1024) void scan_kernel(const int* __restrict__ deg,
                                                    int* __restrict__ offsets,
                                                    int* __restrict__ cursor, int N) {
    extern __shared__ int sm[];          // [N staged deg/run] + [1024 partials]
    int* sdeg = sm;
    int* part = sm + ((N + 1023) & ~1023);
    const int t = threadIdx.x;
    const int CH = (N + 1023) >> 10;
    for (int j = t; j < N; j += 1024) sdeg[j] = deg[j];   // coalesced in
    __syncthreads();
    const int base = t * CH;
    int s = 0;
    for (int j = 0; j < CH; ++j) {
        int idx = base + j;
        if (idx < N) s += sdeg[idx];
    }
    part[t] = s;
    __syncthreads();
    for (int off = 1; off < 1024; off <<= 1) {
        int add = (t >= off) ? part[t - off] : 0;
        __syncthreads();
        part[t] += add;
        __syncthreads();
    }
    int run = (t == 0) ? 0 : part[t - 1];
    for (int j = 0; j < CH; ++j) {
        int idx = base + j;
        if (idx < N) {
            int dgi = sdeg[idx];
            sdeg[idx] = run;             // stage run in place
            run += dgi;
        }
    }
    __syncthreads();
    for (int j = t; j < N; j += 1024) {  // coalesced out x2
        int v = sdeg[j];
        offsets[j] = v;
        cursor[j]  = v;
    }
    if (t == 1023) offsets[N] = run;
}

__global__ __launch_bounds__(256) void fill_kernel(const int* __restrict__ ei,
                                                   int* __restrict__ cursor,
                                                   int* __restrict__ csr, int E) {
    int e = blockIdx.x * 256 + threadIdx.x;
    if (e < E) {
        int dd = ei[E + e];
        int slot = atomicAdd(&cursor[dd], 1);
        csr[slot] = ei[e];
    }
}

// ---------- embedding + BN(layer 0), bf16 into A_cat[:, 0:512] ----------
__global__ __launch_bounds__(256) void embed_bn_kernel(const int* __restrict__ tok,
                                                       const int* __restrict__ pos,
                                                       const float* __restrict__ vemb,
                                                       const float* __restrict__ pemb,
                                                       const float* __restrict__ gamma,
                                                       const float* __restrict__ beta,
                                                       const float* __restrict__ mean,
                                                       const float* __restrict__ var,
                                                       uint32_t* __restrict__ Acat, int N) {
    const int idx = blockIdx.x * 256 + threadIdx.x;   // one per 4 columns
    if (idx >= N * 128) return;
    const int row = idx >> 7;
    const int c = (idx & 127) * 4;
    const int tk = tok[row];
    const int ps = pos[row];
    const float4 a = *(const float4*)&vemb[(size_t)tk * 512 + c];
    const float4 b = *(const float4*)&pemb[(size_t)ps * 512 + c];
    const float4 g = *(const float4*)&gamma[c];
    const float4 be = *(const float4*)&beta[c];
    const float4 mn = *(const float4*)&mean[c];
    const float4 vr = *(const float4*)&var[c];
    const float y0 = (a.x + b.x - mn.x) * (g.x * rsqrtf(vr.x + EPS)) + be.x;
    const float y1 = (a.y + b.y - mn.y) * (g.y * rsqrtf(vr.y + EPS)) + be.y;
    const float y2 = (a.z + b.z - mn.z) * (g.z * rsqrtf(vr.z + EPS)) + be.z;
    const float y3 = (a.w + b.w - mn.w) * (g.w * rsqrtf(vr.w + EPS)) + be.w;
    uint2 o;
    o.x = pack2(y0, y1);
    o.y = pack2(y2, y3);
    *(uint2*)&Acat[(size_t)row * 512 + (c >> 1)] = o;
}

// ---------- W_cat bf16 [512 rows][1024 k] = [W_root | W_rel] (B^T layout) ----------
// per-layer variant (1 MB Wcat)
__global__ __launch_bounds__(256) void castW_kernel(const float* __restrict__ Wroot,
                                                    const float* __restrict__ Wrel,
                                                    uint32_t* __restrict__ Wcat) {
    const int p = blockIdx.x * 256 + threadIdx.x;   // 262144 pairs total
    const int o  = p >> 9;
    const int dp = p & 511;
    float2 v;
    if (dp < 256) v = *(const float2*)&Wroot[(size_t)o * 512 + dp * 2];
    else          v = *(const float2*)&Wrel[(size_t)o * 512 + (dp - 256) * 2];
    Wcat[(size_t)o * 512 + dp] = pack2(v.x, v.y);
}

// all-4-layers variant (4 MB Wcat4, one launch)
__global__ __launch_bounds__(256) void castW4_kernel(const float* __restrict__ Wroot,
                                                     const float* __restrict__ Wrel,
                                                     uint32_t* __restrict__ Wcat4) {
    const int p = blockIdx.x * 256 + threadIdx.x;   // 4*262144 pairs total
    const int l   = p >> 18;
    const int rem = p & 262143;
    const int o   = rem >> 9;
    const int dp  = rem & 511;
    float2 v;
    if (dp < 256) v = *(const float2*)&Wroot[(size_t)l * 262144 + (size_t)o * 512 + dp * 2];
    else          v = *(const float2*)&Wrel[(size_t)l * 262144 + (size_t)o * 512 + (dp - 256) * 2];
    Wcat4[(size_t)l * 262144 + (size_t)o * 512 + dp] = pack2(v.x, v.y);
}

// ---------- mean aggregation (CSR gather, wave-per-node, 16B loads, x8 pipeline) ----------
// r7-proven form. deginv computed inline (1/(end-beg), bit-identical to prior path);
// output stored non-temporally (no reuse before next gemm; avoid evicting gather lines).
__global__ __launch_bounds__(256) void aggregate_kernel(uint32_t* __restrict__ Acat,
                                                        const int* __restrict__ offsets,
                                                        const int* __restrict__ csr,
                                                        int N) {
    const int node = blockIdx.x * 4 + (threadIdx.x >> 6);
    if (node >= N) return;
    const int lane = threadIdx.x & 63;
    const int col = lane * 4;                 // uint index within 256-uint bn half
    const int beg = offsets[node];
    const int end = offsets[node + 1];
    float s[8] = {0.f, 0.f, 0.f, 0.f, 0.f, 0.f, 0.f, 0.f};
    int e = beg;
    for (; e + 8 <= end; e += 8) {
        const int i0 = csr[e];
        const int i1 = csr[e + 1];
        const int i2 = csr[e + 2];
        const int i3 = csr[e + 3];
        const int i4 = csr[e + 4];
        const int i5 = csr[e + 5];
        const int i6 = csr[e + 6];
        const int i7 = csr[e + 7];
        const uint4 p0 = *(const uint4*)&Acat[(size_t)i0 * 512 + col];
        const uint4 p1 = *(const uint4*)&Acat[(size_t)i1 * 512 + col];
        const uint4 p2 = *(const uint4*)&Acat[(size_t)i2 * 512 + col];
        const uint4 p3 = *(const uint4*)&Acat[(size_t)i3 * 512 + col];
        const uint4 p4 = *(const uint4*)&Acat[(size_t)i4 * 512 + col];
        const uint4 p5 = *(const uint4*)&Acat[(size_t)i5 * 512 + col];
        const uint4 p6 = *(const uint4*)&Acat[(size_t)i6 * 512 + col];
        const uint4 p7 = *(const uint4*)&Acat[(size_t)i7 * 512 + col];
        s[0] += (bflo(p0.x) + bflo(p1.x)) + (bflo(p2.x) + bflo(p3.x))
              + (bflo(p4.x) + bflo(p5.x)) + (bflo(p6.x) + bflo(p7.x));
        s[1] += (bfhi(p0.x) + bfhi(p1.x)) + (bfhi(p2.x) + bfhi(p3.x))
              + (bfhi(p4.x) + bfhi(p5.x)) + (bfhi(p6.x) + bfhi(p7.x));
        s[2] += (bflo(p0.y) + bflo(p1.y)) + (bflo(p2.y) + bflo(p3.y))
              + (bflo(p4.y) + bflo(p5.y)) + (bflo(p6.y) + bflo(p7.y));
        s[3] += (bfhi(p0.y) + bfhi(p1.y)) + (bfhi(p2.y) + bfhi(p3.y))
              + (bfhi(p4.y) + bfhi(p5.y)) + (bfhi(p6.y) + bfhi(p7.y));
        s[4] += (bflo(p0.z) + bflo(p1.z)) + (bflo(p2.z) + bflo(p3.z))
              + (bflo(p4.z) + bflo(p5.z)) + (bflo(p6.z) + bflo(p7.z));
        s[5] += (bfhi(p0.z) + bfhi(p1.z)) + (bfhi(p2.z) + bfhi(p3.z))
              + (bfhi(p4.z) + bfhi(p5.z)) + (bfhi(p6.z) + bfhi(p7.z));
        s[6] += (bflo(p0.w) + bflo(p1.w)) + (bflo(p2.w) + bflo(p3.w))
              + (bflo(p4.w) + bflo(p5.w)) + (bflo(p6.w) + bflo(p7.w));
        s[7] += (bfhi(p0.w) + bfhi(p1.w)) + (bfhi(p2.w) + bfhi(p3.w))
              + (bfhi(p4.w) + bfhi(p5.w)) + (bfhi(p6.w) + bfhi(p7.w));
    }
    for (; e + 4 <= end; e += 4) {
        const int i0 = csr[e];
        const int i1 = csr[e + 1];
        const int i2 = csr[e + 2];
        const int i3 = csr[e + 3];
        const uint4 p0 = *(const uint4*)&Acat[(size_t)i0 * 512 + col];
        const uint4 p1 = *(const uint4*)&Acat[(size_t)i1 * 512 + col];
        const uint4 p2 = *(const uint4*)&Acat[(size_t)i2 * 512 + col];
        const uint4 p3 = *(const uint4*)&Acat[(size_t)i3 * 512 + col];
        s[0] += bflo(p0.x) + bflo(p1.x) + bflo(p2.x) + bflo(p3.x);
        s[1] += bfhi(p0.x) + bfhi(p1.x) + bfhi(p2.x) + bfhi(p3.x);
        s[2] += bflo(p0.y) + bflo(p1.y) + bflo(p2.y) + bflo(p3.y);
        s[3] += bfhi(p0.y) + bfhi(p1.y) + bfhi(p2.y) + bfhi(p3.y);
        s[4] += bflo(p0.z) + bflo(p1.z) + bflo(p2.z) + bflo(p3.z);
        s[5] += bfhi(p0.z) + bfhi(p1.z) + bfhi(p2.z) + bfhi(p3.z);
        s[6] += bflo(p0.w) + bflo(p1.w) + bflo(p2.w) + bflo(p3.w);
        s[7] += bfhi(p0.w) + bfhi(p1.w) + bfhi(p2.w) + bfhi(p3.w);
    }
    for (; e < end; ++e) {
        const int i0 = csr[e];
        const uint4 p0 = *(const uint4*)&Acat[(size_t)i0 * 512 + col];
        s[0] += bflo(p0.x); s[1] += bfhi(p0.x);
        s[2] += bflo(p0.y); s[3] += bfhi(p0.y);
        s[4] += bflo(p0.z); s[5] += bfhi(p0.z);
        s[6] += bflo(p0.w); s[7] += bfhi(p0.w);
    }
    const int dgi = end - beg;
    const float inv = 1.0f / (float)(dgi > 0 ? dgi : 1);
    u32x4 o;
    o.x = pack2(s[0] * inv, s[1] * inv);
    o.y = pack2(s[2] * inv, s[3] * inv);
    o.z = pack2(s[4] * inv, s[5] * inv);
    o.w = pack2(s[6] * inv, s[7] * inv);
    __builtin_nontemporal_store(o, (u32x4*)&Acat[(size_t)node * 512 + 256 + col]);
}

// ---------- fused GEMM: out = relu(A_cat[M,1024] @ W_cat[512,1024]^T + bias) ----------
// r7-proven: BK=32, 16 KiB LDS, plain __syncthreads, max TLP + bank-conflict swizzle
// (writer pre-swizzles GLOBAL k-slot, linear LDS dest; reader XORs same key).
__global__ __launch_bounds__(256) void gemm_bt_bias_relu(const unsigned short* __restrict__ A,
                                                         const unsigned short* __restrict__ B,
                                                         const float* __restrict__ bias,
                                                         const float* __restrict__ gamma,
                                                         const float* __restrict__ beta,
                                                         const float* __restrict__ mean,
                                                         const float* __restrict__ var,
                                                         int last,
                                                         float* __restrict__ C,
                                                         unsigned short* __restrict__ Abn,
                                                         int M, int mt, int rpx) {
    __shared__ __align__(16) unsigned short As[128 * 32];
    __shared__ __align__(16) unsigned short Bs[128 * 32];

    const int bid = blockIdx.x;
    const int bm  = (bid & 7) * rpx + ((bid >> 3) >> 2);
    const int bn  = (bid >> 3) & 3;
    if (bm >= mt) return;

    const int t    = threadIdx.x;
    const int lane = t & 63;
    const int wave = t >> 6;
    const int wm = (wave >> 1) * 64;
    const int wn = (wave & 1) * 64;

    const int r  = t >> 2;
    const int kc = t & 3;
    const int kg = kc ^ ((r >> 1) & 3);          // pre-swizzled global 16B k-slot
    int ar0 = bm * 128 + r;      if (ar0 >= M) ar0 = M - 1;
    int ar1 = bm * 128 + r + 64; if (ar1 >= M) ar1 = M - 1;   // (r+64)>>1 & 3 == (r>>1)&3
    const int br0 = bn * 128 + r;
    const int br1 = br0 + 64;

    const unsigned short* ga0 = A + (size_t)ar0 * 1024 + kg * 8;
    const unsigned short* ga1 = A + (size_t)ar1 * 1024 + kg * 8;
    const unsigned short* gb0 = B + (size_t)br0 * 1024 + kg * 8;
    const unsigned short* gb1 = B + (size_t)br1 * 1024 + kg * 8;

    unsigned short* la0 = &As[r * 32 + kc * 8];          // linear LDS dest
    unsigned short* la1 = &As[(r + 64) * 32 + kc * 8];
    unsigned short* lb0 = &Bs[r * 32 + kc * 8];
    unsigned short* lb1 = &Bs[(r + 64) * 32 + kc * 8];

    const f32x4 zero = {0.f, 0.f, 0.f, 0.f};
    f32x4 acc[4][4];
#pragma unroll
    for (int i = 0; i < 4; ++i)
#pragma unroll
        for (int j = 0; j < 4; ++j) acc[i][j] = zero;

    const int lm = lane & 15;
    const int q  = lane >> 4;
    const int qs = (q ^ ((lm >> 1) & 3)) * 8;    // swizzled read slot (per-lane const)

    for (int k0 = 0; k0 < 1024; k0 += 32) {
        async_ld16(ga0 + k0, la0);
        async_ld16(ga1 + k0, la1);
        async_ld16(gb0 + k0, lb0);
        async_ld16(gb1 + k0, lb1);
        __syncthreads();

        bf16x8 afr[4], bfr[4];
#pragma unroll
        for (int mt2 = 0; mt2 < 4; ++mt2)
            afr[mt2] = *(const bf16x8*)&As[(wm + mt2 * 16 + lm) * 32 + qs];
#pragma unroll
        for (int nt = 0; nt < 4; ++nt)
            bfr[nt] = *(const bf16x8*)&Bs[(wn + nt * 16 + lm) * 32 + qs];
#pragma unroll
        for (int mt2 = 0; mt2 < 4; ++mt2)
#pragma unroll
            for (int nt = 0; nt < 4; ++nt)
                acc[mt2][nt] = __builtin_amdgcn_mfma_f32_16x16x32_bf16(afr[mt2], bfr[nt],
                                                                       acc[mt2][nt], 0, 0, 0);
        __syncthreads();
    }

    // epilogue: C/D layout col=lane&15, row=(lane>>4)*4+reg (m89-verified)
#pragma unroll
    for (int nt = 0; nt < 4; ++nt) {
        const int col = bn * 128 + wn + nt * 16 + lm;
        const float bv = bias[col];
        float bn_inv = 0.f, bn_mb = 0.f;
        if (!last) {
            bn_inv = gamma[col] * rsqrtf(var[col] + EPS);
            bn_mb  = mean[col];
        }
        const float bn_beta = last ? 0.f : beta[col];
#pragma unroll
        for (int mt2 = 0; mt2 < 4; ++mt2) {
            const int row0 = bm * 128 + wm + mt2 * 16 + q * 4;
#pragma unroll
            for (int i = 0; i < 4; ++i) {
                const int row = row0 + i;
                if (row < M) {
                    float v = acc[mt2][nt][i] + bv;
                    v = v > 0.f ? v : 0.f;
                    if (last) {
                        C[(size_t)row * 512 + col] = v;
                    } else {
                        const float y = (v - bn_mb) * bn_inv + bn_beta;
                        Abn[(size_t)row * 1024 + col] = f2bf(y);
                    }
                }
            }
        }
    }
}

extern "C" void kernel_launch(void* const* d_in, const int* in_sizes, int n_in,
                              void* d_out, int out_size, void* d_ws, size_t ws_size,
                              hipStream_t stream) {
    const int*   tokens = (const int*)d_in[0];
    const int*   posi   = (const int*)d_in[1];
    const int*   ei     = (const int*)d_in[2];
    const float* vemb   = (const float*)d_in[3];
    const float* pemb   = (const float*)d_in[4];
    const float* gamma  = (const float*)d_in[5];
    const float* beta   = (const float*)d_in[6];
    const float* mean   = (const float*)d_in[7];
    const float* var    = (const float*)d_in[8];
    const float* Wrel   = (const float*)d_in[9];
    const float* brel   = (const float*)d_in[10];
    const float* Wroot  = (const float*)d_in[11];

    const int N = in_sizes[0];
    const int E = in_sizes[2] / 2;
    float* out = (float*)d_out;

    char* w = (char*)d_ws;
    int*      deg     = (int*)(w);                  // N ints
    int*      offsets = (int*)(w + 80000);          // N+1 ints
    int*      cursor  = (int*)(w + 160016);         // N ints
    int*      csr     = (int*)(w + 320048);         // E ints
    uint32_t* Acat    = (uint32_t*)(w + 1600064);   // [N][512] uints = [N][1024] bf16
    uint32_t* Wcat    = (uint32_t*)(w + 42560064);  // 1 MB (or 4 MB batched)

    // batched castW needs 4 MB at Wcat (end = 46,754,368 bytes)
    const int batched = (ws_size >= 46754368ull) ? 1 : 0;

    // scan uses dynamic LDS: N-staged deg (rounded to 1024) + 1024 partials
    const int scan_lds = (((N + 1023) & ~1023) + 1024) * 4;
    static bool s_attr = false;
    if (!s_attr) {
        (void)hipFuncSetAttribute(reinterpret_cast<const void*>(scan_kernel),
                                  hipFuncAttributeMaxDynamicSharedMemorySize, 163840);
        s_attr = true;
    }

    // CSR build (ws re-poisoned each call -> deg must be zeroed here)
    (void)hipMemsetAsync(deg, 0, (size_t)N * 4, stream);
    count_kernel<<<(E + 255) / 256, 256, 0, stream>>>(ei, deg, E);
    scan_kernel<<<1, 1024, scan_lds, stream>>>(deg, offsets, cursor, N);
    fill_kernel<<<(E + 255) / 256, 256, 0, stream>>>(ei, cursor, csr, E);

    // embed + layer-0 BN directly into Acat (no f32 x round-trip)
    embed_bn_kernel<<<(N * 128 + 255) / 256, 256, 0, stream>>>(
        tokens, posi, vemb, pemb, gamma, beta, mean, var, Acat, N);

    if (batched)
        castW4_kernel<<<4096, 256, 0, stream>>>(Wroot, Wrel, Wcat);

    const int mt  = (N + 127) >> 7;    // 128-row tiles (158)
    const int rpx = (mt + 7) >> 3;     // row-tiles per XCD (20)
    const int gb  = 8 * rpx * 4;       // grid (640; tail blocks exit early)

    for (int l = 0; l < 4; ++l) {
        const int last = (l == 3);
        if (!batched)
            castW_kernel<<<1024, 256, 0, stream>>>(Wroot + (size_t)l * 262144,
                                                   Wrel + (size_t)l * 262144, Wcat);
        aggregate_kernel<<<(N + 3) / 4, 256, 0, stream>>>(Acat, offsets, csr, N);
        const uint32_t* Wl = batched ? (Wcat + (size_t)l * 262144) : Wcat;
        gemm_bt_bias_relu<<<gb, 256, 0, stream>>>(
            (const unsigned short*)Acat, (const unsigned short*)Wl, brel + l * 512,
            gamma + (l + 1) * 512, beta + (l + 1) * 512,
            mean + (l + 1) * 512, var + (l + 1) * 512,
            last, out, (unsigned short*)Acat, N, mt, rpx);
    }
}

// Round 11
// 508.329 us; speedup vs baseline: 1.1270x; 1.0326x over previous
//
#include <hip/hip_runtime.h>
#include <cstdint>

#define EPS 1e-5f

typedef __attribute__((ext_vector_type(8))) short bf16x8;   // 8 bf16 in 4 VGPRs
typedef __attribute__((ext_vector_type(4))) float f32x4;
typedef __attribute__((ext_vector_type(4))) unsigned int u32x4;  // native vec for nt-store

// ---------- bf16 helpers (RNE) ----------
__device__ __forceinline__ unsigned short f2bf(float x) {
    uint32_t u = __float_as_uint(x);
    u += 0x7fffu + ((u >> 16) & 1u);
    return (unsigned short)(u >> 16);
}
__device__ __forceinline__ uint32_t pack2(float lo, float hi) {
    return (uint32_t)f2bf(lo) | ((uint32_t)f2bf(hi) << 16);
}
__device__ __forceinline__ float bflo(uint32_t p) { return __uint_as_float(p << 16); }
__device__ __forceinline__ float bfhi(uint32_t p) { return __uint_as_float(p & 0xffff0000u); }

// ---------- async global->LDS, 16B per lane ----------
__device__ __forceinline__ void async_ld16(const void* g, const void* l) {
    __builtin_amdgcn_global_load_lds(
        (const __attribute__((address_space(1))) uint32_t*)(uintptr_t)g,
        (__attribute__((address_space(3))) uint32_t*)(uint32_t)(uintptr_t)l,
        16, 0, 0);
}

// ---------- CSR build ----------
__global__ __launch_bounds__(256) void count_kernel(const int* __restrict__ ei,
                                                    int* __restrict__ deg, int E) {
    int e = blockIdx.x * 256 + threadIdx.x;
    if (e < E) atomicAdd(&deg[ei[E + e]], 1);
}

// LDS-staged scan: coalesced deg loads, prefix over 1024 chunk-partials,
// run values staged back into LDS, coalesced offsets/cursor writeout.
__global__ __launch_bounds__(1024) void scan_kernel(const int* __restrict__ deg,
                                                    int* __restrict__ offsets,
                                                    int* __restrict__ cursor, int N) {
    extern __shared__ int sm[];          // [N staged deg/run] + [1024 partials]
    int* sdeg = sm;
    int* part = sm + ((N + 1023) & ~1023);
    const int t = threadIdx.x;
    const int CH = (N + 1023) >> 10;
    for (int j = t; j < N; j += 1024) sdeg[j] = deg[j];   // coalesced in
    __syncthreads();
    const int base = t * CH;
    int s = 0;
    for (int j = 0; j < CH; ++j) {
        int idx = base + j;
        if (idx < N) s += sdeg[idx];
    }
    part[t] = s;
    __syncthreads();
    for (int off = 1; off < 1024; off <<= 1) {
        int add = (t >= off) ? part[t - off] : 0;
        __syncthreads();
        part[t] += add;
        __syncthreads();
    }
    int run = (t == 0) ? 0 : part[t - 1];
    for (int j = 0; j < CH; ++j) {
        int idx = base + j;
        if (idx < N) {
            int dgi = sdeg[idx];
            sdeg[idx] = run;             // stage run in place
            run += dgi;
        }
    }
    __syncthreads();
    for (int j = t; j < N; j += 1024) {  // coalesced out x2
        int v = sdeg[j];
        offsets[j] = v;
        cursor[j]  = v;
    }
    if (t == 1023) offsets[N] = run;
}

__global__ __launch_bounds__(256) void fill_kernel(const int* __restrict__ ei,
                                                   int* __restrict__ cursor,
                                                   int* __restrict__ csr, int E) {
    int e = blockIdx.x * 256 + threadIdx.x;
    if (e < E) {
        int dd = ei[E + e];
        int slot = atomicAdd(&cursor[dd], 1);
        csr[slot] = ei[e];
    }
}

// ---------- embedding + BN(layer 0), bf16 into A_cat[:, 0:512] ----------
__global__ __launch_bounds__(256) void embed_bn_kernel(const int* __restrict__ tok,
                                                       const int* __restrict__ pos,
                                                       const float* __restrict__ vemb,
                                                       const float* __restrict__ pemb,
                                                       const float* __restrict__ gamma,
                                                       const float* __restrict__ beta,
                                                       const float* __restrict__ mean,
                                                       const float* __restrict__ var,
                                                       uint32_t* __restrict__ Acat, int N) {
    const int idx = blockIdx.x * 256 + threadIdx.x;   // one per 4 columns
    if (idx >= N * 128) return;
    const int row = idx >> 7;
    const int c = (idx & 127) * 4;
    const int tk = tok[row];
    const int ps = pos[row];
    const float4 a = *(const float4*)&vemb[(size_t)tk * 512 + c];
    const float4 b = *(const float4*)&pemb[(size_t)ps * 512 + c];
    const float4 g = *(const float4*)&gamma[c];
    const float4 be = *(const float4*)&beta[c];
    const float4 mn = *(const float4*)&mean[c];
    const float4 vr = *(const float4*)&var[c];
    const float y0 = (a.x + b.x - mn.x) * (g.x * rsqrtf(vr.x + EPS)) + be.x;
    const float y1 = (a.y + b.y - mn.y) * (g.y * rsqrtf(vr.y + EPS)) + be.y;
    const float y2 = (a.z + b.z - mn.z) * (g.z * rsqrtf(vr.z + EPS)) + be.z;
    const float y3 = (a.w + b.w - mn.w) * (g.w * rsqrtf(vr.w + EPS)) + be.w;
    uint2 o;
    o.x = pack2(y0, y1);
    o.y = pack2(y2, y3);
    *(uint2*)&Acat[(size_t)row * 512 + (c >> 1)] = o;
}

// ---------- W_cat bf16 [512 rows][1024 k] = [W_root | W_rel] (B^T layout) ----------
// per-layer variant (1 MB Wcat)
__global__ __launch_bounds__(256) void castW_kernel(const float* __restrict__ Wroot,
                                                    const float* __restrict__ Wrel,
                                                    uint32_t* __restrict__ Wcat) {
    const int p = blockIdx.x * 256 + threadIdx.x;   // 262144 pairs total
    const int o  = p >> 9;
    const int dp = p & 511;
    float2 v;
    if (dp < 256) v = *(const float2*)&Wroot[(size_t)o * 512 + dp * 2];
    else          v = *(const float2*)&Wrel[(size_t)o * 512 + (dp - 256) * 2];
    Wcat[(size_t)o * 512 + dp] = pack2(v.x, v.y);
}

// all-4-layers variant (4 MB Wcat4, one launch)
__global__ __launch_bounds__(256) void castW4_kernel(const float* __restrict__ Wroot,
                                                     const float* __restrict__ Wrel,
                                                     uint32_t* __restrict__ Wcat4) {
    const int p = blockIdx.x * 256 + threadIdx.x;   // 4*262144 pairs total
    const int l   = p >> 18;
    const int rem = p & 262143;
    const int o   = rem >> 9;
    const int dp  = rem & 511;
    float2 v;
    if (dp < 256) v = *(const float2*)&Wroot[(size_t)l * 262144 + (size_t)o * 512 + dp * 2];
    else          v = *(const float2*)&Wrel[(size_t)l * 262144 + (size_t)o * 512 + (dp - 256) * 2];
    Wcat4[(size_t)l * 262144 + (size_t)o * 512 + dp] = pack2(v.x, v.y);
}

// ---------- mean aggregation (CSR gather, wave-per-node, 16B loads, x8 pipeline) ----------
// r10-proven form (inline deginv, nt-store).
__global__ __launch_bounds__(256) void aggregate_kernel(uint32_t* __restrict__ Acat,
                                                        const int* __restrict__ offsets,
                                                        const int* __restrict__ csr,
                                                        int N) {
    const int node = blockIdx.x * 4 + (threadIdx.x >> 6);
    if (node >= N) return;
    const int lane = threadIdx.x & 63;
    const int col = lane * 4;                 // uint index within 256-uint bn half
    const int beg = offsets[node];
    const int end = offsets[node + 1];
    float s[8] = {0.f, 0.f, 0.f, 0.f, 0.f, 0.f, 0.f, 0.f};
    int e = beg;
    for (; e + 8 <= end; e += 8) {
        const int i0 = csr[e];
        const int i1 = csr[e + 1];
        const int i2 = csr[e + 2];
        const int i3 = csr[e + 3];
        const int i4 = csr[e + 4];
        const int i5 = csr[e + 5];
        const int i6 = csr[e + 6];
        const int i7 = csr[e + 7];
        const uint4 p0 = *(const uint4*)&Acat[(size_t)i0 * 512 + col];
        const uint4 p1 = *(const uint4*)&Acat[(size_t)i1 * 512 + col];
        const uint4 p2 = *(const uint4*)&Acat[(size_t)i2 * 512 + col];
        const uint4 p3 = *(const uint4*)&Acat[(size_t)i3 * 512 + col];
        const uint4 p4 = *(const uint4*)&Acat[(size_t)i4 * 512 + col];
        const uint4 p5 = *(const uint4*)&Acat[(size_t)i5 * 512 + col];
        const uint4 p6 = *(const uint4*)&Acat[(size_t)i6 * 512 + col];
        const uint4 p7 = *(const uint4*)&Acat[(size_t)i7 * 512 + col];
        s[0] += (bflo(p0.x) + bflo(p1.x)) + (bflo(p2.x) + bflo(p3.x))
              + (bflo(p4.x) + bflo(p5.x)) + (bflo(p6.x) + bflo(p7.x));
        s[1] += (bfhi(p0.x) + bfhi(p1.x)) + (bfhi(p2.x) + bfhi(p3.x))
              + (bfhi(p4.x) + bfhi(p5.x)) + (bfhi(p6.x) + bfhi(p7.x));
        s[2] += (bflo(p0.y) + bflo(p1.y)) + (bflo(p2.y) + bflo(p3.y))
              + (bflo(p4.y) + bflo(p5.y)) + (bflo(p6.y) + bflo(p7.y));
        s[3] += (bfhi(p0.y) + bfhi(p1.y)) + (bfhi(p2.y) + bfhi(p3.y))
              + (bfhi(p4.y) + bfhi(p5.y)) + (bfhi(p6.y) + bfhi(p7.y));
        s[4] += (bflo(p0.z) + bflo(p1.z)) + (bflo(p2.z) + bflo(p3.z))
              + (bflo(p4.z) + bflo(p5.z)) + (bflo(p6.z) + bflo(p7.z));
        s[5] += (bfhi(p0.z) + bfhi(p1.z)) + (bfhi(p2.z) + bfhi(p3.z))
              + (bfhi(p4.z) + bfhi(p5.z)) + (bfhi(p6.z) + bfhi(p7.z));
        s[6] += (bflo(p0.w) + bflo(p1.w)) + (bflo(p2.w) + bflo(p3.w))
              + (bflo(p4.w) + bflo(p5.w)) + (bflo(p6.w) + bflo(p7.w));
        s[7] += (bfhi(p0.w) + bfhi(p1.w)) + (bfhi(p2.w) + bfhi(p3.w))
              + (bfhi(p4.w) + bfhi(p5.w)) + (bfhi(p6.w) + bfhi(p7.w));
    }
    for (; e + 4 <= end; e += 4) {
        const int i0 = csr[e];
        const int i1 = csr[e + 1];
        const int i2 = csr[e + 2];
        const int i3 = csr[e + 3];
        const uint4 p0 = *(const uint4*)&Acat[(size_t)i0 * 512 + col];
        const uint4 p1 = *(const uint4*)&Acat[(size_t)i1 * 512 + col];
        const uint4 p2 = *(const uint4*)&Acat[(size_t)i2 * 512 + col];
        const uint4 p3 = *(const uint4*)&Acat[(size_t)i3 * 512 + col];
        s[0] += bflo(p0.x) + bflo(p1.x) + bflo(p2.x) + bflo(p3.x);
        s[1] += bfhi(p0.x) + bfhi(p1.x) + bfhi(p2.x) + bfhi(p3.x);
        s[2] += bflo(p0.y) + bflo(p1.y) + bflo(p2.y) + bflo(p3.y);
        s[3] += bfhi(p0.y) + bfhi(p1.y) + bfhi(p2.y) + bfhi(p3.y);
        s[4] += bflo(p0.z) + bflo(p1.z) + bflo(p2.z) + bflo(p3.z);
        s[5] += bfhi(p0.z) + bfhi(p1.z) + bfhi(p2.z) + bfhi(p3.z);
        s[6] += bflo(p0.w) + bflo(p1.w) + bflo(p2.w) + bflo(p3.w);
        s[7] += bfhi(p0.w) + bfhi(p1.w) + bfhi(p2.w) + bfhi(p3.w);
    }
    for (; e < end; ++e) {
        const int i0 = csr[e];
        const uint4 p0 = *(const uint4*)&Acat[(size_t)i0 * 512 + col];
        s[0] += bflo(p0.x); s[1] += bfhi(p0.x);
        s[2] += bflo(p0.y); s[3] += bfhi(p0.y);
        s[4] += bflo(p0.z); s[5] += bfhi(p0.z);
        s[6] += bflo(p0.w); s[7] += bfhi(p0.w);
    }
    const int dgi = end - beg;
    const float inv = 1.0f / (float)(dgi > 0 ? dgi : 1);
    u32x4 o;
    o.x = pack2(s[0] * inv, s[1] * inv);
    o.y = pack2(s[2] * inv, s[3] * inv);
    o.z = pack2(s[4] * inv, s[5] * inv);
    o.w = pack2(s[6] * inv, s[7] * inv);
    __builtin_nontemporal_store(o, (u32x4*)&Acat[(size_t)node * 512 + 256 + col]);
}

// ---------- fused GEMM: out = relu(A_cat[M,1024] @ W_cat[512,1024]^T + bias) ----------
// r7 structure + double-buffered LDS (32 KiB), ONE raw barrier per K-step:
//   iter k: vmcnt(0) [drains loads issued a full K-step earlier -> nearly free]
//           s_barrier [publish buf[k&1]: all waves' loads retired before anyone passes]
//           stage buf[(k+1)&1] [WAR-safe: last readers (iter k-1) proved complete by
//                               their own lgkmcnt-before-MFMA, then barrier_k]
//           ds_read buf[k&1] -> 32 MFMA  [compiler inserts lgkmcnt]
// vs r7's stage->__syncthreads(vmcnt0 on JUST-issued loads = full latency every step).
// Bank-conflict swizzle unchanged (writer pre-swizzles GLOBAL k-slot, linear LDS dest).
__global__ __launch_bounds__(256) void gemm_bt_bias_relu(const unsigned short* __restrict__ A,
                                                         const unsigned short* __restrict__ B,
                                                         const float* __restrict__ bias,
                                                         const float* __restrict__ gamma,
                                                         const float* __restrict__ beta,
                                                         const float* __restrict__ mean,
                                                         const float* __restrict__ var,
                                                         int last,
                                                         float* __restrict__ C,
                                                         unsigned short* __restrict__ Abn,
                                                         int M, int mt, int rpx) {
    __shared__ __align__(16) unsigned short As[2][128 * 32];
    __shared__ __align__(16) unsigned short Bs[2][128 * 32];

    const int bid = blockIdx.x;
    const int bm  = (bid & 7) * rpx + ((bid >> 3) >> 2);
    const int bn  = (bid >> 3) & 3;
    if (bm >= mt) return;

    const int t    = threadIdx.x;
    const int lane = t & 63;
    const int wave = t >> 6;
    const int wm = (wave >> 1) * 64;
    const int wn = (wave & 1) * 64;

    const int r  = t >> 2;
    const int kc = t & 3;
    const int kg = kc ^ ((r >> 1) & 3);          // pre-swizzled global 16B k-slot
    int ar0 = bm * 128 + r;      if (ar0 >= M) ar0 = M - 1;
    int ar1 = bm * 128 + r + 64; if (ar1 >= M) ar1 = M - 1;   // (r+64)>>1 & 3 == (r>>1)&3
    const int br0 = bn * 128 + r;
    const int br1 = br0 + 64;

    const unsigned short* ga0 = A + (size_t)ar0 * 1024 + kg * 8;
    const unsigned short* ga1 = A + (size_t)ar1 * 1024 + kg * 8;
    const unsigned short* gb0 = B + (size_t)br0 * 1024 + kg * 8;
    const unsigned short* gb1 = B + (size_t)br1 * 1024 + kg * 8;

    const int lofA0 = r * 32 + kc * 8;           // linear LDS dest offsets
    const int lofA1 = (r + 64) * 32 + kc * 8;

    const f32x4 zero = {0.f, 0.f, 0.f, 0.f};
    f32x4 acc[4][4];
#pragma unroll
    for (int i = 0; i < 4; ++i)
#pragma unroll
        for (int j = 0; j < 4; ++j) acc[i][j] = zero;

    const int lm = lane & 15;
    const int q  = lane >> 4;
    const int qs = (q ^ ((lm >> 1) & 3)) * 8;    // swizzled read slot (per-lane const)

    // prologue: stage k=0 into buf 0
    async_ld16(ga0, &As[0][lofA0]);
    async_ld16(ga1, &As[0][lofA1]);
    async_ld16(gb0, &Bs[0][lofA0]);
    async_ld16(gb1, &Bs[0][lofA1]);

#pragma unroll 2
    for (int ks = 0; ks < 32; ++ks) {
        const int cur = ks & 1;
        const int nxt = cur ^ 1;
        // publish buf[cur]: own loads (issued >= 1 iter ago) retired, then rendezvous
        asm volatile("s_waitcnt vmcnt(0)" ::: "memory");
        __builtin_amdgcn_s_barrier();
        __builtin_amdgcn_sched_barrier(0);
        // stage next tile (overlaps this iter's ds_read+MFMA; WAR-safe per barrier proof)
        if (ks < 31) {
            const int k1 = (ks + 1) * 32;
            async_ld16(ga0 + k1, &As[nxt][lofA0]);
            async_ld16(ga1 + k1, &As[nxt][lofA1]);
            async_ld16(gb0 + k1, &Bs[nxt][lofA0]);
            async_ld16(gb1 + k1, &Bs[nxt][lofA1]);
        }
        bf16x8 afr[4], bfr[4];
#pragma unroll
        for (int mt2 = 0; mt2 < 4; ++mt2)
            afr[mt2] = *(const bf16x8*)&As[cur][(wm + mt2 * 16 + lm) * 32 + qs];
#pragma unroll
        for (int nt = 0; nt < 4; ++nt)
            bfr[nt] = *(const bf16x8*)&Bs[cur][(wn + nt * 16 + lm) * 32 + qs];
#pragma unroll
        for (int mt2 = 0; mt2 < 4; ++mt2)
#pragma unroll
            for (int nt = 0; nt < 4; ++nt)
                acc[mt2][nt] = __builtin_amdgcn_mfma_f32_16x16x32_bf16(afr[mt2], bfr[nt],
                                                                       acc[mt2][nt], 0, 0, 0);
    }

    // epilogue: C/D layout col=lane&15, row=(lane>>4)*4+reg (m89-verified)
#pragma unroll
    for (int nt = 0; nt < 4; ++nt) {
        const int col = bn * 128 + wn + nt * 16 + lm;
        const float bv = bias[col];
        float bn_inv = 0.f, bn_mb = 0.f;
        if (!last) {
            bn_inv = gamma[col] * rsqrtf(var[col] + EPS);
            bn_mb  = mean[col];
        }
        const float bn_beta = last ? 0.f : beta[col];
#pragma unroll
        for (int mt2 = 0; mt2 < 4; ++mt2) {
            const int row0 = bm * 128 + wm + mt2 * 16 + q * 4;
#pragma unroll
            for (int i = 0; i < 4; ++i) {
                const int row = row0 + i;
                if (row < M) {
                    float v = acc[mt2][nt][i] + bv;
                    v = v > 0.f ? v : 0.f;
                    if (last) {
                        C[(size_t)row * 512 + col] = v;
                    } else {
                        const float y = (v - bn_mb) * bn_inv + bn_beta;
                        Abn[(size_t)row * 1024 + col] = f2bf(y);
                    }
                }
            }
        }
    }
}

extern "C" void kernel_launch(void* const* d_in, const int* in_sizes, int n_in,
                              void* d_out, int out_size, void* d_ws, size_t ws_size,
                              hipStream_t stream) {
    const int*   tokens = (const int*)d_in[0];
    const int*   posi   = (const int*)d_in[1];
    const int*   ei     = (const int*)d_in[2];
    const float* vemb   = (const float*)d_in[3];
    const float* pemb   = (const float*)d_in[4];
    const float* gamma  = (const float*)d_in[5];
    const float* beta   = (const float*)d_in[6];
    const float* mean   = (const float*)d_in[7];
    const float* var    = (const float*)d_in[8];
    const float* Wrel   = (const float*)d_in[9];
    const float* brel   = (const float*)d_in[10];
    const float* Wroot  = (const float*)d_in[11];

    const int N = in_sizes[0];
    const int E = in_sizes[2] / 2;
    float* out = (float*)d_out;

    char* w = (char*)d_ws;
    int*      deg     = (int*)(w);                  // N ints
    int*      offsets = (int*)(w + 80000);          // N+1 ints
    int*      cursor  = (int*)(w + 160016);         // N ints
    int*      csr     = (int*)(w + 320048);         // E ints
    uint32_t* Acat    = (uint32_t*)(w + 1600064);   // [N][512] uints = [N][1024] bf16
    uint32_t* Wcat    = (uint32_t*)(w + 42560064);  // 1 MB (or 4 MB batched)

    // batched castW needs 4 MB at Wcat (end = 46,754,368 bytes)
    const int batched = (ws_size >= 46754368ull) ? 1 : 0;

    // scan uses dynamic LDS: N-staged deg (rounded to 1024) + 1024 partials
    const int scan_lds = (((N + 1023) & ~1023) + 1024) * 4;
    static bool s_attr = false;
    if (!s_attr) {
        (void)hipFuncSetAttribute(reinterpret_cast<const void*>(scan_kernel),
                                  hipFuncAttributeMaxDynamicSharedMemorySize, 163840);
        s_attr = true;
    }

    // CSR build (ws re-poisoned each call -> deg must be zeroed here)
    (void)hipMemsetAsync(deg, 0, (size_t)N * 4, stream);
    count_kernel<<<(E + 255) / 256, 256, 0, stream>>>(ei, deg, E);
    scan_kernel<<<1, 1024, scan_lds, stream>>>(deg, offsets, cursor, N);
    fill_kernel<<<(E + 255) / 256, 256, 0, stream>>>(ei, cursor, csr, E);

    // embed + layer-0 BN directly into Acat (no f32 x round-trip)
    embed_bn_kernel<<<(N * 128 + 255) / 256, 256, 0, stream>>>(
        tokens, posi, vemb, pemb, gamma, beta, mean, var, Acat, N);

    if (batched)
        castW4_kernel<<<4096, 256, 0, stream>>>(Wroot, Wrel, Wcat);

    const int mt  = (N + 127) >> 7;    // 128-row tiles (158)
    const int rpx = (mt + 7) >> 3;     // row-tiles per XCD (20)
    const int gb  = 8 * rpx * 4;       // grid (640; tail blocks exit early)

    for (int l = 0; l < 4; ++l) {
        const int last = (l == 3);
        if (!batched)
            castW_kernel<<<1024, 256, 0, stream>>>(Wroot + (size_t)l * 262144,
                                                   Wrel + (size_t)l * 262144, Wcat);
        aggregate_kernel<<<(N + 3) / 4, 256, 0, stream>>>(Acat, offsets, csr, N);
        const uint32_t* Wl = batched ? (Wcat + (size_t)l * 262144) : Wcat;
        gemm_bt_bias_relu<<<gb, 256, 0, stream>>>(
            (const unsigned short*)Acat, (const unsigned short*)Wl, brel + l * 512,
            gamma + (l + 1) * 512, beta + (l + 1) * 512,
            mean + (l + 1) * 512, var + (l + 1) * 512,
            last, out, (unsigned short*)Acat, N, mt, rpx);
    }
}